// Round 5
// baseline (338.752 us; speedup 1.0000x reference)
//
#include <hip/hip_runtime.h>
#include <hip/hip_bf16.h>

// FlexibleGCN forward on MI355X — Round 13:
//  * Degree-class node permutation for agg: nodes sorted into 16 classes by
//    trip count (padded_deg/8); agg waves process 8 same-class nodes ->
//    no intra-wave loop divergence (was ~64% lane efficiency, Poisson deg).
//  * 3 tiny perm kernels (count/scan/assign) derive classes from rows[].
//  * agg unchanged otherwise: CSR-vector 8 lanes/node, uint4 gathers,
//    depth-8 in flight, pad-to-8 tail-free (R12, 51us -> predict ~40us).

constexpr int IN_DIM  = 128;
constexpr int HDIM    = 64;
constexpr int NBLK_A  = 256;   // blocks in pass A (must match histg stride)
constexpr int BSH     = 8;     // bucket shift: 256 nodes per bucket
constexpr int MAXNB   = 512;   // max buckets supported (N <= 131072)
constexpr int PADSLK  = 1792;  // per-bucket esrc slack: 256 nodes x 7 max pad
constexpr int NCLASS  = 16;    // degree classes (trip count, clamped)

__device__ __forceinline__ float bf2f(unsigned int u) {
    return __uint_as_float(u << 16);
}
__device__ __forceinline__ unsigned short f2bf_bits(float f) {
    __hip_bfloat16 b = __float2bfloat16(f);
    return *(unsigned short*)&b;
}

// ---------- CSR build ----------

__global__ void binA_count(const int* __restrict__ dst, int* __restrict__ histg,
                           int E, int NB, int chunk) {
    __shared__ int h[MAXNB];
    for (int i = threadIdx.x; i < NB; i += 256) h[i] = 0;
    __syncthreads();
    int beg = blockIdx.x * chunk;
    int end = min(E, beg + chunk);
    for (int e = beg + threadIdx.x; e < end; e += 256)
        atomicAdd(&h[dst[e] >> BSH], 1);
    __syncthreads();
    for (int i = threadIdx.x; i < NB; i += 256)
        histg[i * NBLK_A + blockIdx.x] = h[i];
}

__global__ void binA_scanblocks(int* __restrict__ histg, int* __restrict__ btot) {
    __shared__ int sm[NBLK_A];
    int tid = threadIdx.x;
    int v = histg[blockIdx.x * NBLK_A + tid];
    sm[tid] = v;
    __syncthreads();
    for (int off = 1; off < NBLK_A; off <<= 1) {
        int t = (tid >= off) ? sm[tid - off] : 0;
        __syncthreads();
        sm[tid] += t;
        __syncthreads();
    }
    histg[blockIdx.x * NBLK_A + tid] = sm[tid] - v;   // exclusive
    if (tid == NBLK_A - 1) btot[blockIdx.x] = sm[tid];
}

__global__ void binA_scanbuckets(const int* __restrict__ btot, int* __restrict__ bucketbase,
                                 int NB) {
    __shared__ int sm[MAXNB];
    int tid = threadIdx.x;    // blockDim = MAXNB
    int v = (tid < NB) ? btot[tid] : 0;
    sm[tid] = v;
    __syncthreads();
    for (int off = 1; off < MAXNB; off <<= 1) {
        int t = (tid >= off) ? sm[tid - off] : 0;
        __syncthreads();
        sm[tid] += t;
        __syncthreads();
    }
    if (tid < NB) bucketbase[tid] = sm[tid] - v;
    if (tid == MAXNB - 1) bucketbase[NB] = sm[tid];   // == E
}

__global__ void binA_scatter(const int* __restrict__ src, const int* __restrict__ dst,
                             const int* __restrict__ histg, const int* __restrict__ bucketbase,
                             int* __restrict__ staging, int E, int NB, int chunk) {
    __shared__ int cur[MAXNB];
    for (int i = threadIdx.x; i < NB; i += 256)
        cur[i] = bucketbase[i] + histg[i * NBLK_A + blockIdx.x];
    __syncthreads();
    int beg = blockIdx.x * chunk;
    int end = min(E, beg + chunk);
    for (int e = beg + threadIdx.x; e < end; e += 256) {
        int s = src[e];
        int d = dst[e];
        int pos = atomicAdd(&cur[d >> BSH], 1);
        staging[pos] = (s << BSH) | (d & 255);    // src<2^17, local dst 8 bits
    }
}

// Builds padded CSR: per-node range rounded up to a multiple of 8; pad
// slots point at node N (whose hp row is zeroed here). rows[n]=(beg,end).
__global__ void binB_finalize(const int* __restrict__ staging, const int* __restrict__ bucketbase,
                              int2* __restrict__ rows, int* __restrict__ esrc,
                              float* __restrict__ dinv, unsigned int* __restrict__ hp_rowN,
                              int* __restrict__ classCnt, int N, int NB) {
    __shared__ int cnt[256], sm[256], cur[256];
    int tid = threadIdx.x;
    int b = blockIdx.x;
    int node0 = b << BSH;
    int nloc = min(256, N - node0);
    int ebeg = bucketbase[b], eend = bucketbase[b + 1];
    int ebegP = ebeg + b * PADSLK;            // padded bucket base
    cnt[tid] = 0;
    if (b == 0 && tid < NCLASS) classCnt[tid] = 0;   // for perm build (later)
    __syncthreads();
    for (int e = ebeg + tid; e < eend; e += 256)
        atomicAdd(&cnt[staging[e] & 255], 1);
    __syncthreads();
    int v = cnt[tid];
    int pv = (v + 7) & ~7;                    // padded count
    sm[tid] = pv;
    __syncthreads();
    for (int off = 1; off < 256; off <<= 1) {
        int t = (tid >= off) ? sm[tid - off] : 0;
        __syncthreads();
        sm[tid] += t;
        __syncthreads();
    }
    int excl = sm[tid] - pv;                  // padded exclusive offset
    cur[tid] = excl;
    __syncthreads();
    if (tid < nloc) {
        rows[node0 + tid] = make_int2(ebegP + excl, ebegP + excl + pv);
        dinv[node0 + tid] = rsqrtf((float)v + 1.0f);   // +1 self-loop
        for (int q = v; q < pv; ++q)          // fill pad slots -> zero row
            esrc[ebegP + excl + q] = N;
    }
    if (b == 0 && tid < 32) hp_rowN[tid] = 0u;         // zero hp row N (128B)
    for (int e = ebeg + tid; e < eend; e += 256) {
        int p = staging[e];
        int pos = ebegP + atomicAdd(&cur[p & 255], 1);
        esrc[pos] = p >> BSH;
    }
}

// ---------- degree-class permutation ----------

__device__ __forceinline__ int trip_class(int2 be) {
    return min((be.y - be.x) >> 3, NCLASS - 1);
}

__global__ void classCount(const int2* __restrict__ rows, int* __restrict__ classCnt, int N) {
    __shared__ int lc[NCLASS];
    if (threadIdx.x < NCLASS) lc[threadIdx.x] = 0;
    __syncthreads();
    int i = blockIdx.x * 256 + threadIdx.x;
    if (i < N) atomicAdd(&lc[trip_class(rows[i])], 1);
    __syncthreads();
    if (threadIdx.x < NCLASS) atomicAdd(&classCnt[threadIdx.x], lc[threadIdx.x]);
}

__global__ void classScan(const int* __restrict__ classCnt, int* __restrict__ classCur) {
    if (threadIdx.x == 0) {
        int base = 0;
        for (int t = 0; t < NCLASS; ++t) {
            classCur[t] = base;
            base += classCnt[t];
        }
    }
}

__global__ void classAssign(const int2* __restrict__ rows, int* __restrict__ classCur,
                            int* __restrict__ perm, int N) {
    __shared__ int lc[NCLASS], lbase[NCLASS];
    if (threadIdx.x < NCLASS) lc[threadIdx.x] = 0;
    __syncthreads();
    int i = blockIdx.x * 256 + threadIdx.x;
    int t = -1, r = 0;
    if (i < N) {
        t = trip_class(rows[i]);
        r = atomicAdd(&lc[t], 1);       // rank within block
    }
    __syncthreads();
    if (threadIdx.x < NCLASS && lc[threadIdx.x] > 0)
        lbase[threadIdx.x] = atomicAdd(&classCur[threadIdx.x], lc[threadIdx.x]);
    __syncthreads();
    if (i < N) perm[lbase[t] + r] = i;
}

// ---------- dense layers ----------

// Y[n][64] = X[n][K] @ W[K][64]; optional *dinv[row], optional +bias.
// 256 threads, tile 128 rows x 64 cols; thread = 8x4 micro-tile; KC=32.
template<int K, bool IBF16, bool SCALE, bool BIAS, bool OBF16>
__device__ __forceinline__ void gemm_body(
        const void* __restrict__ Xv, const float* __restrict__ W,
        const float* __restrict__ bias, const float* __restrict__ dinv,
        void* __restrict__ Yv, int n) {
    constexpr int KC = 32;
    constexpr int XSTR = 132;                 // floats
    __shared__ float Xt[KC * XSTR];           // 16.9 KB
    __shared__ float Ws[KC * 64];             // 8 KB
    const int tid = threadIdx.x;
    const int node0 = blockIdx.x * 128;
    const int r0 = (tid >> 4) * 8;            // 0..120
    const int c0 = (tid & 15) * 4;            // 0..60

    float acc[8][4];
#pragma unroll
    for (int a = 0; a < 8; ++a)
#pragma unroll
        for (int b = 0; b < 4; ++b) acc[a][b] = 0.f;

    for (int kc = 0; kc < K; kc += KC) {
        __syncthreads();
#pragma unroll
        for (int i = 0; i < 4; ++i) {
            int s = tid + i * 256;
            int row = s >> 3;
            int kq = s & 7;
            int grow = node0 + row;
            float4 v = make_float4(0.f, 0.f, 0.f, 0.f);
            if (grow < n) {
                if (IBF16) {
                    uint2 u = *(const uint2*)&((const unsigned short*)Xv)[(size_t)grow * K + kc + kq * 4];
                    v.x = bf2f(u.x & 0xffff); v.y = bf2f(u.x >> 16);
                    v.z = bf2f(u.y & 0xffff); v.w = bf2f(u.y >> 16);
                } else {
                    v = *(const float4*)&((const float*)Xv)[(size_t)grow * K + kc + kq * 4];
                }
            }
            Xt[(kq * 4 + 0) * XSTR + row] = v.x;
            Xt[(kq * 4 + 1) * XSTR + row] = v.y;
            Xt[(kq * 4 + 2) * XSTR + row] = v.z;
            Xt[(kq * 4 + 3) * XSTR + row] = v.w;
        }
#pragma unroll
        for (int i = 0; i < 2; ++i) {
            int s = tid + i * 256;
            *(float4*)&Ws[s * 4] = *(const float4*)&W[(size_t)kc * 64 + s * 4];
        }
        __syncthreads();
#pragma unroll
        for (int kk = 0; kk < KC; kk += 4) {
            float4 xa[4][2];
            float4 wv[4];
#pragma unroll
            for (int i = 0; i < 4; ++i) {
                xa[i][0] = *(const float4*)&Xt[(kk + i) * XSTR + r0];
                xa[i][1] = *(const float4*)&Xt[(kk + i) * XSTR + r0 + 4];
                wv[i]    = *(const float4*)&Ws[(kk + i) * 64 + c0];
            }
#pragma unroll
            for (int i = 0; i < 4; ++i) {
                const float* xp = (const float*)&xa[i][0];
                const float* wp = (const float*)&wv[i];
#pragma unroll
                for (int rr = 0; rr < 8; ++rr)
#pragma unroll
                    for (int cc = 0; cc < 4; ++cc)
                        acc[rr][cc] += xp[rr] * wp[cc];
            }
        }
    }
#pragma unroll
    for (int rr = 0; rr < 8; ++rr) {
        int node = node0 + r0 + rr;
        if (node < n) {
            float d = SCALE ? dinv[node] : 1.0f;
            float t[4];
#pragma unroll
            for (int cc = 0; cc < 4; ++cc) {
                float v = acc[rr][cc];
                if (BIAS) v += bias[c0 + cc];
                t[cc] = v * d;
            }
            if (OBF16) {
                __hip_bfloat16 vb[4];
#pragma unroll
                for (int cc = 0; cc < 4; ++cc) vb[cc] = __float2bfloat16(t[cc]);
                *(uint2*)&((__hip_bfloat16*)Yv)[(size_t)node * 64 + c0] = *(uint2*)vb;
            } else {
                *(float4*)&((float*)Yv)[(size_t)node * 64 + c0] = *(float4*)t;
            }
        }
    }
}

__global__ __launch_bounds__(256, 4) void gemm1_kernel(
        const float* X, const float* W, const float* dinv, void* Y, int n) {
    gemm_body<IN_DIM, false, true, false, true>(X, W, nullptr, dinv, Y, n);
}
__global__ __launch_bounds__(256, 4) void gemm2_kernel(
        const void* X, const float* W, const float* dinv, void* Y, int n) {
    gemm_body<HDIM, true, true, false, true>(X, W, nullptr, dinv, Y, n);
}
__global__ __launch_bounds__(256, 4) void fc_kernel(
        const float* X, const float* W, const float* bias, void* Y, int n) {
    gemm_body<HDIM, false, false, true, false>(X, W, bias, nullptr, Y, n);
}

// ---------- aggregation: CSR-vector, 8 lanes per node, degree-sorted ----------
// Wave = 8 nodes x 8 lanes, nodes drawn from perm[] (degree-class-sorted ->
// all 8 groups run the same trip count; no intra-wave divergence).
// Lane j holds feats 8j..8j+7 (uint4 = 16B of the 128B bf16 row). Depth-8
// unroll: 8 independent row-gathers in flight; edge lists padded to %8.
template<bool OBF16>
__global__ __launch_bounds__(256) void agg_kernel(
        const uint4* __restrict__ hp4, const int* __restrict__ esrc,
        const int2* __restrict__ rows, const float* __restrict__ dinv,
        const float* __restrict__ bias, const int* __restrict__ perm,
        void* __restrict__ out, int n) {
    const int lane = threadIdx.x & 63;
    const int j = lane & 7;
    const int idx = blockIdx.x * 32 + (threadIdx.x >> 6) * 8 + (lane >> 3);
    if (idx >= n) return;
    const int node = perm[idx];
    const int2 be = rows[node];

    float acc[8];
    {   // self-loop: own row
        uint4 u = hp4[(size_t)node * 8 + j];
        acc[0] = bf2f(u.x & 0xffff); acc[1] = bf2f(u.x >> 16);
        acc[2] = bf2f(u.y & 0xffff); acc[3] = bf2f(u.y >> 16);
        acc[4] = bf2f(u.z & 0xffff); acc[5] = bf2f(u.z >> 16);
        acc[6] = bf2f(u.w & 0xffff); acc[7] = bf2f(u.w >> 16);
    }
    for (int k = be.x; k < be.y; k += 8) {
        int s[8];
#pragma unroll
        for (int i = 0; i < 8; ++i)
            s[i] = __builtin_nontemporal_load(&esrc[k + i]);
        uint4 u[8];
#pragma unroll
        for (int i = 0; i < 8; ++i)
            u[i] = hp4[(size_t)s[i] * 8 + j];
#pragma unroll
        for (int i = 0; i < 8; ++i) {
            acc[0] += bf2f(u[i].x & 0xffff); acc[1] += bf2f(u[i].x >> 16);
            acc[2] += bf2f(u[i].y & 0xffff); acc[3] += bf2f(u[i].y >> 16);
            acc[4] += bf2f(u[i].z & 0xffff); acc[5] += bf2f(u[i].z >> 16);
            acc[6] += bf2f(u[i].w & 0xffff); acc[7] += bf2f(u[i].w >> 16);
        }
    }
    const float d = dinv[node];
    float o[8];
#pragma unroll
    for (int t = 0; t < 8; ++t)
        o[t] = fmaxf(fmaf(d, acc[t], bias[8 * j + t]), 0.f);

    if (OBF16) {
        uint4 pk;
        pk.x = (unsigned)f2bf_bits(o[0]) | ((unsigned)f2bf_bits(o[1]) << 16);
        pk.y = (unsigned)f2bf_bits(o[2]) | ((unsigned)f2bf_bits(o[3]) << 16);
        pk.z = (unsigned)f2bf_bits(o[4]) | ((unsigned)f2bf_bits(o[5]) << 16);
        pk.w = (unsigned)f2bf_bits(o[6]) | ((unsigned)f2bf_bits(o[7]) << 16);
        ((uint4*)out)[(size_t)node * 8 + j] = pk;
    } else {
        ((float4*)out)[(size_t)node * 16 + 2 * j]     = make_float4(o[0], o[1], o[2], o[3]);
        ((float4*)out)[(size_t)node * 16 + 2 * j + 1] = make_float4(o[4], o[5], o[6], o[7]);
    }
}

extern "C" void kernel_launch(void* const* d_in, const int* in_sizes, int n_in,
                              void* d_out, int out_size, void* d_ws, size_t ws_size,
                              hipStream_t stream) {
    const float* x   = (const float*)d_in[0];
    const float* W1  = (const float*)d_in[1];
    const float* b1  = (const float*)d_in[2];
    const float* W2  = (const float*)d_in[3];
    const float* b2  = (const float*)d_in[4];
    const float* Wfc = (const float*)d_in[5];
    const float* bfc = (const float*)d_in[6];
    const int*  eidx = (const int*)d_in[7];

    const int N = in_sizes[0] / IN_DIM;     // 100000
    const int E = in_sizes[7] / 2;          // 1600000
    const int* src = eidx;
    const int* dst = eidx + E;

    const int NB    = (N + 255) >> BSH;     // 391 buckets
    const int chunk = (E + NBLK_A - 1) / NBLK_A;
    const int EP    = E + NB * PADSLK;      // padded esrc capacity

    // ws layout (ints, regions 16B-aligned):
    // rows[N] (int2) | dinv[N] | histg[NB*256] | btot[512] | bucketbase[512]
    //   | classCnt[16] | classCur[16] | perm[N]
    //   | esrc[EP] | hp[(N+1)*32] (bf16 rows, row N = zero) | h1[N*32]
    // staging int[E] aliases hp (dead before gemm1 writes hp).
    int* p = (int*)d_ws;
    int2* rows = (int2*)p;           p += (size_t)2 * N + 2;
    float* dinv = (float*)p;         p += (size_t)((N + 3) & ~3);
    int* histg = p;                  p += (size_t)((NB * NBLK_A + 3) & ~3);
    int* btot = p;                   p += 512;
    int* bucketbase = p;             p += 512;
    int* classCnt = p;               p += NCLASS;
    int* classCur = p;               p += NCLASS;
    int* perm = p;                   p += (size_t)((N + 3) & ~3);
    int* esrc = p;                   p += (size_t)((EP + 3) & ~3);
    unsigned short* hp = (unsigned short*)p;   p += (size_t)(N + 1) * 32;
    unsigned short* h1 = (unsigned short*)p;   p += (size_t)N * 32;
    int* staging = (int*)hp;                   // E ints < (N+1)*32 ints
    unsigned int* hp_rowN = (unsigned int*)(hp + (size_t)N * 64);

    float* emb    = (float*)d_out;
    float* logits = emb + (size_t)N * HDIM;

    const int nBlocks256 = (N + 255) / 256;

    // ---- CSR build (shared by both conv layers) ----
    binA_count<<<NBLK_A, 256, 0, stream>>>(dst, histg, E, NB, chunk);
    binA_scanblocks<<<NB, NBLK_A, 0, stream>>>(histg, btot);
    binA_scanbuckets<<<1, MAXNB, 0, stream>>>(btot, bucketbase, NB);
    binA_scatter<<<NBLK_A, 256, 0, stream>>>(src, dst, histg, bucketbase, staging, E, NB, chunk);
    binB_finalize<<<NB, 256, 0, stream>>>(staging, bucketbase, rows, esrc, dinv, hp_rowN,
                                          classCnt, N, NB);

    // ---- degree-class permutation (removes agg wave divergence) ----
    classCount<<<nBlocks256, 256, 0, stream>>>(rows, classCnt, N);
    classScan<<<1, 64, 0, stream>>>(classCnt, classCur);
    classAssign<<<nBlocks256, 256, 0, stream>>>(rows, classCur, perm, N);

    const int gBlocks = (N + 127) / 128;
    const int aBlocks = (N + 31) / 32;

    // ---- layer 1 ----
    gemm1_kernel<<<gBlocks, 256, 0, stream>>>(x, W1, dinv, hp, N);
    agg_kernel<true><<<aBlocks, 256, 0, stream>>>(
        (const uint4*)hp, esrc, rows, dinv, b1, perm, h1, N);

    // ---- layer 2 ----
    gemm2_kernel<<<gBlocks, 256, 0, stream>>>(h1, W2, dinv, hp, N);
    agg_kernel<false><<<aBlocks, 256, 0, stream>>>(
        (const uint4*)hp, esrc, rows, dinv, b2, perm, emb, N);

    // ---- FC head ----
    fc_kernel<<<gBlocks, 256, 0, stream>>>(emb, Wfc, bfc, logits, N);
}

// Round 6
// 314.764 us; speedup vs baseline: 1.0762x; 1.0762x over previous
//
#include <hip/hip_runtime.h>
#include <hip/hip_bf16.h>

// FlexibleGCN forward on MI355X — Round 14:
//  * Revert R13 perm (divergence theory falsified: BW-bound at ~3.7TB/s).
//  * agg: depth-16 gather batches (16 uint4 in flight, ~96 VGPR) + exact
//    2048-block grid-stride fill (R12's 3125 blocks -> 1.5 sched waves).
//  * CSR: binA_scanbuckets removed; scatter + finalize compute the bucket
//    prefix in-block from btot (one fewer dispatch).
//  * Rest identical to R12 (CSR-vector agg, pad-to-8, separate fc).

constexpr int IN_DIM  = 128;
constexpr int HDIM    = 64;
constexpr int NBLK_A  = 256;   // blocks in pass A (must match histg stride)
constexpr int BSH     = 8;     // bucket shift: 256 nodes per bucket
constexpr int MAXNB   = 512;   // max buckets supported (N <= 131072)
constexpr int PADSLK  = 1792;  // per-bucket esrc slack: 256 nodes x 7 max pad

__device__ __forceinline__ float bf2f(unsigned int u) {
    return __uint_as_float(u << 16);
}
__device__ __forceinline__ unsigned short f2bf_bits(float f) {
    __hip_bfloat16 b = __float2bfloat16(f);
    return *(unsigned short*)&b;
}

// ---------- CSR build ----------

__global__ void binA_count(const int* __restrict__ dst, int* __restrict__ histg,
                           int E, int NB, int chunk) {
    __shared__ int h[MAXNB];
    for (int i = threadIdx.x; i < NB; i += 256) h[i] = 0;
    __syncthreads();
    int beg = blockIdx.x * chunk;
    int end = min(E, beg + chunk);
    for (int e = beg + threadIdx.x; e < end; e += 256)
        atomicAdd(&h[dst[e] >> BSH], 1);
    __syncthreads();
    for (int i = threadIdx.x; i < NB; i += 256)
        histg[i * NBLK_A + blockIdx.x] = h[i];
}

__global__ void binA_scanblocks(int* __restrict__ histg, int* __restrict__ btot) {
    __shared__ int sm[NBLK_A];
    int tid = threadIdx.x;
    int v = histg[blockIdx.x * NBLK_A + tid];
    sm[tid] = v;
    __syncthreads();
    for (int off = 1; off < NBLK_A; off <<= 1) {
        int t = (tid >= off) ? sm[tid - off] : 0;
        __syncthreads();
        sm[tid] += t;
        __syncthreads();
    }
    histg[blockIdx.x * NBLK_A + tid] = sm[tid] - v;   // exclusive
    if (tid == NBLK_A - 1) btot[blockIdx.x] = sm[tid];
}

// In-block inclusive scan of btot[0..NB) over MAXNB entries (256 threads,
// 2 elements/thread). bb[] ends inclusive; exclusive = bb[i] - btot[i].
__device__ __forceinline__ void bucket_scan(const int* __restrict__ btot,
                                            int* bb, int NB) {
    int tid = threadIdx.x;
    for (int i = tid; i < MAXNB; i += 256) bb[i] = (i < NB) ? btot[i] : 0;
    __syncthreads();
    for (int off = 1; off < MAXNB; off <<= 1) {
        int i0 = tid, i1 = tid + 256;
        int t0 = (i0 >= off) ? bb[i0 - off] : 0;
        int t1 = (i1 >= off) ? bb[i1 - off] : 0;
        __syncthreads();
        bb[i0] += t0;
        bb[i1] += t1;
        __syncthreads();
    }
}

__global__ void binA_scatter(const int* __restrict__ src, const int* __restrict__ dst,
                             const int* __restrict__ histg, const int* __restrict__ btot,
                             int* __restrict__ staging, int E, int NB, int chunk) {
    __shared__ int bb[MAXNB];
    __shared__ int cur[MAXNB];
    bucket_scan(btot, bb, NB);
    for (int i = threadIdx.x; i < NB; i += 256)
        cur[i] = (bb[i] - btot[i]) + histg[i * NBLK_A + blockIdx.x];
    __syncthreads();
    int beg = blockIdx.x * chunk;
    int end = min(E, beg + chunk);
    for (int e = beg + threadIdx.x; e < end; e += 256) {
        int s = src[e];
        int d = dst[e];
        int pos = atomicAdd(&cur[d >> BSH], 1);
        staging[pos] = (s << BSH) | (d & 255);    // src<2^17, local dst 8 bits
    }
}

// Builds padded CSR: per-node range rounded up to a multiple of 8; pad
// slots point at node N (whose hp row is zeroed here). rows[n]=(beg,end).
__global__ void binB_finalize(const int* __restrict__ staging, const int* __restrict__ btot,
                              int2* __restrict__ rows, int* __restrict__ esrc,
                              float* __restrict__ dinv, unsigned int* __restrict__ hp_rowN,
                              int N, int NB) {
    __shared__ int bb[MAXNB];
    __shared__ int cnt[256], sm[256], cur[256];
    int tid = threadIdx.x;
    int b = blockIdx.x;
    bucket_scan(btot, bb, NB);
    int node0 = b << BSH;
    int nloc = min(256, N - node0);
    int eend = bb[b];
    int ebeg = eend - btot[b];
    int ebegP = ebeg + b * PADSLK;            // padded bucket base
    cnt[tid] = 0;
    __syncthreads();
    for (int e = ebeg + tid; e < eend; e += 256)
        atomicAdd(&cnt[staging[e] & 255], 1);
    __syncthreads();
    int v = cnt[tid];
    int pv = (v + 7) & ~7;                    // padded count
    sm[tid] = pv;
    __syncthreads();
    for (int off = 1; off < 256; off <<= 1) {
        int t = (tid >= off) ? sm[tid - off] : 0;
        __syncthreads();
        sm[tid] += t;
        __syncthreads();
    }
    int excl = sm[tid] - pv;                  // padded exclusive offset
    cur[tid] = excl;
    __syncthreads();
    if (tid < nloc) {
        rows[node0 + tid] = make_int2(ebegP + excl, ebegP + excl + pv);
        dinv[node0 + tid] = rsqrtf((float)v + 1.0f);   // +1 self-loop
        for (int q = v; q < pv; ++q)          // fill pad slots -> zero row
            esrc[ebegP + excl + q] = N;
    }
    if (b == 0 && tid < 32) hp_rowN[tid] = 0u;         // zero hp row N (128B)
    for (int e = ebeg + tid; e < eend; e += 256) {
        int p = staging[e];
        int pos = ebegP + atomicAdd(&cur[p & 255], 1);
        esrc[pos] = p >> BSH;
    }
}

// ---------- dense layers ----------

// Y[n][64] = X[n][K] @ W[K][64]; optional *dinv[row], optional +bias.
// 256 threads, tile 128 rows x 64 cols; thread = 8x4 micro-tile; KC=32.
template<int K, bool IBF16, bool SCALE, bool BIAS, bool OBF16>
__device__ __forceinline__ void gemm_body(
        const void* __restrict__ Xv, const float* __restrict__ W,
        const float* __restrict__ bias, const float* __restrict__ dinv,
        void* __restrict__ Yv, int n) {
    constexpr int KC = 32;
    constexpr int XSTR = 132;                 // floats
    __shared__ float Xt[KC * XSTR];           // 16.9 KB
    __shared__ float Ws[KC * 64];             // 8 KB
    const int tid = threadIdx.x;
    const int node0 = blockIdx.x * 128;
    const int r0 = (tid >> 4) * 8;            // 0..120
    const int c0 = (tid & 15) * 4;            // 0..60

    float acc[8][4];
#pragma unroll
    for (int a = 0; a < 8; ++a)
#pragma unroll
        for (int b = 0; b < 4; ++b) acc[a][b] = 0.f;

    for (int kc = 0; kc < K; kc += KC) {
        __syncthreads();
#pragma unroll
        for (int i = 0; i < 4; ++i) {
            int s = tid + i * 256;
            int row = s >> 3;
            int kq = s & 7;
            int grow = node0 + row;
            float4 v = make_float4(0.f, 0.f, 0.f, 0.f);
            if (grow < n) {
                if (IBF16) {
                    uint2 u = *(const uint2*)&((const unsigned short*)Xv)[(size_t)grow * K + kc + kq * 4];
                    v.x = bf2f(u.x & 0xffff); v.y = bf2f(u.x >> 16);
                    v.z = bf2f(u.y & 0xffff); v.w = bf2f(u.y >> 16);
                } else {
                    v = *(const float4*)&((const float*)Xv)[(size_t)grow * K + kc + kq * 4];
                }
            }
            Xt[(kq * 4 + 0) * XSTR + row] = v.x;
            Xt[(kq * 4 + 1) * XSTR + row] = v.y;
            Xt[(kq * 4 + 2) * XSTR + row] = v.z;
            Xt[(kq * 4 + 3) * XSTR + row] = v.w;
        }
#pragma unroll
        for (int i = 0; i < 2; ++i) {
            int s = tid + i * 256;
            *(float4*)&Ws[s * 4] = *(const float4*)&W[(size_t)kc * 64 + s * 4];
        }
        __syncthreads();
#pragma unroll
        for (int kk = 0; kk < KC; kk += 4) {
            float4 xa[4][2];
            float4 wv[4];
#pragma unroll
            for (int i = 0; i < 4; ++i) {
                xa[i][0] = *(const float4*)&Xt[(kk + i) * XSTR + r0];
                xa[i][1] = *(const float4*)&Xt[(kk + i) * XSTR + r0 + 4];
                wv[i]    = *(const float4*)&Ws[(kk + i) * 64 + c0];
            }
#pragma unroll
            for (int i = 0; i < 4; ++i) {
                const float* xp = (const float*)&xa[i][0];
                const float* wp = (const float*)&wv[i];
#pragma unroll
                for (int rr = 0; rr < 8; ++rr)
#pragma unroll
                    for (int cc = 0; cc < 4; ++cc)
                        acc[rr][cc] += xp[rr] * wp[cc];
            }
        }
    }
#pragma unroll
    for (int rr = 0; rr < 8; ++rr) {
        int node = node0 + r0 + rr;
        if (node < n) {
            float d = SCALE ? dinv[node] : 1.0f;
            float t[4];
#pragma unroll
            for (int cc = 0; cc < 4; ++cc) {
                float v = acc[rr][cc];
                if (BIAS) v += bias[c0 + cc];
                t[cc] = v * d;
            }
            if (OBF16) {
                __hip_bfloat16 vb[4];
#pragma unroll
                for (int cc = 0; cc < 4; ++cc) vb[cc] = __float2bfloat16(t[cc]);
                *(uint2*)&((__hip_bfloat16*)Yv)[(size_t)node * 64 + c0] = *(uint2*)vb;
            } else {
                *(float4*)&((float*)Yv)[(size_t)node * 64 + c0] = *(float4*)t;
            }
        }
    }
}

__global__ __launch_bounds__(256, 4) void gemm1_kernel(
        const float* X, const float* W, const float* dinv, void* Y, int n) {
    gemm_body<IN_DIM, false, true, false, true>(X, W, nullptr, dinv, Y, n);
}
__global__ __launch_bounds__(256, 4) void gemm2_kernel(
        const void* X, const float* W, const float* dinv, void* Y, int n) {
    gemm_body<HDIM, true, true, false, true>(X, W, nullptr, dinv, Y, n);
}
__global__ __launch_bounds__(256, 4) void fc_kernel(
        const float* X, const float* W, const float* bias, void* Y, int n) {
    gemm_body<HDIM, false, false, true, false>(X, W, bias, nullptr, Y, n);
}

// ---------- aggregation: CSR-vector, 8 lanes per node ----------
// Wave = 8 nodes x 8 lanes. Lane j holds feats 8j..8j+7 (uint4 = 16B of the
// 128B bf16 row). Depth-16 main batch (16 independent row-gathers in
// flight) + one depth-8 batch for the padded remainder. Grid-stride with
// exactly 2048 blocks (256 CU x 8) for even fill.
template<bool OBF16>
__global__ __launch_bounds__(256) void agg_kernel(
        const uint4* __restrict__ hp4, const int* __restrict__ esrc,
        const int2* __restrict__ rows, const float* __restrict__ dinv,
        const float* __restrict__ bias, void* __restrict__ out, int n) {
    const int lane = threadIdx.x & 63;
    const int j = lane & 7;
    const int step = gridDim.x * 32;
    for (int idx = blockIdx.x * 32 + (threadIdx.x >> 6) * 8 + (lane >> 3);
         idx < n; idx += step) {
        const int node = idx;
        const int2 be = rows[node];

        float acc[8];
        {   // self-loop: own row
            uint4 u = hp4[(size_t)node * 8 + j];
            acc[0] = bf2f(u.x & 0xffff); acc[1] = bf2f(u.x >> 16);
            acc[2] = bf2f(u.y & 0xffff); acc[3] = bf2f(u.y >> 16);
            acc[4] = bf2f(u.z & 0xffff); acc[5] = bf2f(u.z >> 16);
            acc[6] = bf2f(u.w & 0xffff); acc[7] = bf2f(u.w >> 16);
        }
        int k = be.x;
        for (; k + 16 <= be.y; k += 16) {       // depth-16 batches
            int s[16];
#pragma unroll
            for (int i = 0; i < 16; ++i)
                s[i] = __builtin_nontemporal_load(&esrc[k + i]);
            uint4 u[16];
#pragma unroll
            for (int i = 0; i < 16; ++i)
                u[i] = hp4[(size_t)s[i] * 8 + j];
#pragma unroll
            for (int i = 0; i < 16; ++i) {
                acc[0] += bf2f(u[i].x & 0xffff); acc[1] += bf2f(u[i].x >> 16);
                acc[2] += bf2f(u[i].y & 0xffff); acc[3] += bf2f(u[i].y >> 16);
                acc[4] += bf2f(u[i].z & 0xffff); acc[5] += bf2f(u[i].z >> 16);
                acc[6] += bf2f(u[i].w & 0xffff); acc[7] += bf2f(u[i].w >> 16);
            }
        }
        if (k < be.y) {                          // padded => exactly 8 left
            int s[8];
#pragma unroll
            for (int i = 0; i < 8; ++i)
                s[i] = __builtin_nontemporal_load(&esrc[k + i]);
            uint4 u[8];
#pragma unroll
            for (int i = 0; i < 8; ++i)
                u[i] = hp4[(size_t)s[i] * 8 + j];
#pragma unroll
            for (int i = 0; i < 8; ++i) {
                acc[0] += bf2f(u[i].x & 0xffff); acc[1] += bf2f(u[i].x >> 16);
                acc[2] += bf2f(u[i].y & 0xffff); acc[3] += bf2f(u[i].y >> 16);
                acc[4] += bf2f(u[i].z & 0xffff); acc[5] += bf2f(u[i].z >> 16);
                acc[6] += bf2f(u[i].w & 0xffff); acc[7] += bf2f(u[i].w >> 16);
            }
        }
        const float d = dinv[node];
        float o[8];
#pragma unroll
        for (int t = 0; t < 8; ++t)
            o[t] = fmaxf(fmaf(d, acc[t], bias[8 * j + t]), 0.f);

        if (OBF16) {
            uint4 pk;
            pk.x = (unsigned)f2bf_bits(o[0]) | ((unsigned)f2bf_bits(o[1]) << 16);
            pk.y = (unsigned)f2bf_bits(o[2]) | ((unsigned)f2bf_bits(o[3]) << 16);
            pk.z = (unsigned)f2bf_bits(o[4]) | ((unsigned)f2bf_bits(o[5]) << 16);
            pk.w = (unsigned)f2bf_bits(o[6]) | ((unsigned)f2bf_bits(o[7]) << 16);
            ((uint4*)out)[(size_t)node * 8 + j] = pk;
        } else {
            ((float4*)out)[(size_t)node * 16 + 2 * j]     = make_float4(o[0], o[1], o[2], o[3]);
            ((float4*)out)[(size_t)node * 16 + 2 * j + 1] = make_float4(o[4], o[5], o[6], o[7]);
        }
    }
}

extern "C" void kernel_launch(void* const* d_in, const int* in_sizes, int n_in,
                              void* d_out, int out_size, void* d_ws, size_t ws_size,
                              hipStream_t stream) {
    const float* x   = (const float*)d_in[0];
    const float* W1  = (const float*)d_in[1];
    const float* b1  = (const float*)d_in[2];
    const float* W2  = (const float*)d_in[3];
    const float* b2  = (const float*)d_in[4];
    const float* Wfc = (const float*)d_in[5];
    const float* bfc = (const float*)d_in[6];
    const int*  eidx = (const int*)d_in[7];

    const int N = in_sizes[0] / IN_DIM;     // 100000
    const int E = in_sizes[7] / 2;          // 1600000
    const int* src = eidx;
    const int* dst = eidx + E;

    const int NB    = (N + 255) >> BSH;     // 391 buckets
    const int chunk = (E + NBLK_A - 1) / NBLK_A;
    const int EP    = E + NB * PADSLK;      // padded esrc capacity

    // ws layout (ints, regions 16B-aligned):
    // rows[N] (int2) | dinv[N] | histg[NB*256] | btot[512]
    //   | esrc[EP] | hp[(N+1)*32] (bf16 rows, row N = zero) | h1[N*32]
    // staging int[E] aliases hp (dead before gemm1 writes hp).
    int* p = (int*)d_ws;
    int2* rows = (int2*)p;           p += (size_t)2 * N + 2;
    float* dinv = (float*)p;         p += (size_t)((N + 3) & ~3);
    int* histg = p;                  p += (size_t)((NB * NBLK_A + 3) & ~3);
    int* btot = p;                   p += 512;
    int* esrc = p;                   p += (size_t)((EP + 3) & ~3);
    unsigned short* hp = (unsigned short*)p;   p += (size_t)(N + 1) * 32;
    unsigned short* h1 = (unsigned short*)p;   p += (size_t)N * 32;
    int* staging = (int*)hp;                   // E ints < (N+1)*32 ints
    unsigned int* hp_rowN = (unsigned int*)(hp + (size_t)N * 64);

    float* emb    = (float*)d_out;
    float* logits = emb + (size_t)N * HDIM;

    // ---- CSR build (shared by both conv layers) ----
    binA_count<<<NBLK_A, 256, 0, stream>>>(dst, histg, E, NB, chunk);
    binA_scanblocks<<<NB, NBLK_A, 0, stream>>>(histg, btot);
    binA_scatter<<<NBLK_A, 256, 0, stream>>>(src, dst, histg, btot, staging, E, NB, chunk);
    binB_finalize<<<NB, 256, 0, stream>>>(staging, btot, rows, esrc, dinv, hp_rowN, N, NB);

    const int gBlocks = (N + 127) / 128;
    const int aBlocks = 2048;               // 256 CU x 8 blocks, grid-stride

    // ---- layer 1 ----
    gemm1_kernel<<<gBlocks, 256, 0, stream>>>(x, W1, dinv, hp, N);
    agg_kernel<true><<<aBlocks, 256, 0, stream>>>(
        (const uint4*)hp, esrc, rows, dinv, b1, h1, N);

    // ---- layer 2 ----
    gemm2_kernel<<<gBlocks, 256, 0, stream>>>(h1, W2, dinv, hp, N);
    agg_kernel<false><<<aBlocks, 256, 0, stream>>>(
        (const uint4*)hp, esrc, rows, dinv, b2, emb, N);

    // ---- FC head ----
    fc_kernel<<<gBlocks, 256, 0, stream>>>(emb, Wfc, bfc, logits, N);
}